// Round 1
// baseline (371.963 us; speedup 1.0000x reference)
//
#include <hip/hip_runtime.h>
#include <hip/hip_bf16.h>
#include <math.h>

#define NQ 900
#define NT 100
#define BS 16
#define NH 7
#define NC 16

#define LSA_THREADS 256
#define COLS_PER_THREAD 4   // 4*256 = 1024 >= 901 columns (incl. virtual col 0)

// ---------------- Stage 1: cost matrix (transposed: [b][t][q]) ----------------
__global__ void cost_kernel(const float* __restrict__ logits,   // (7,16,900,16)
                            const float* __restrict__ pboxes,   // (16,900,4)
                            const float* __restrict__ tboxes,   // (16,100,4)
                            const int*   __restrict__ tlabels,  // (7,16,100)
                            float* __restrict__ costT) {        // (16,100,900)
    int id = blockIdx.x * blockDim.x + threadIdx.x;
    if (id >= BS * NT * NQ) return;
    int q = id % NQ;
    int t = (id / NQ) % NT;
    int b = id / (NQ * NT);

    const float* pb = pboxes + (b * NQ + q) * 4;
    const float* tb = tboxes + (b * NT + t) * 4;
    float px = pb[0], py = pb[1], pw = pb[2], ph = pb[3];
    float tx = tb[0], ty = tb[1], tw = tb[2], th = tb[3];

    // L1 on raw cxcywh
    float cost_bbox = fabsf(px - tx) + fabsf(py - ty) + fabsf(pw - tw) + fabsf(ph - th);

    // GIoU on xyxy
    float ax0 = px - 0.5f * pw, ay0 = py - 0.5f * ph;
    float ax1 = px + 0.5f * pw, ay1 = py + 0.5f * ph;
    float bx0 = tx - 0.5f * tw, by0 = ty - 0.5f * th;
    float bx1 = tx + 0.5f * tw, by1 = ty + 0.5f * th;
    float areaA = (ax1 - ax0) * (ay1 - ay0);
    float areaB = (bx1 - bx0) * (by1 - by0);
    float ltx = fmaxf(ax0, bx0), lty = fmaxf(ay0, by0);
    float rbx = fminf(ax1, bx1), rby = fminf(ay1, by1);
    float iw = fmaxf(rbx - ltx, 0.f), ih = fmaxf(rby - lty, 0.f);
    float inter = iw * ih;
    float uni = areaA + areaB - inter;
    float iou = inter / uni;
    float ex0 = fminf(ax0, bx0), ey0 = fminf(ay0, by0);
    float ex1 = fmaxf(ax1, bx1), ey1 = fmaxf(ay1, by1);
    float ew = fmaxf(ex1 - ex0, 0.f), eh = fmaxf(ey1 - ey0, 0.f);
    float earea = ew * eh;
    float giou = iou - (earea - uni) / earea;

    // label cost: -sum_h sigmoid(logits[h,b,q,label(h,b,t)])
    float ssum = 0.f;
    #pragma unroll
    for (int h = 0; h < NH; ++h) {
        int lab = tlabels[(h * BS + b) * NT + t];
        float x = logits[((h * BS + b) * NQ + q) * NC + lab];
        ssum += 1.0f / (1.0f + expf(-x));
    }

    float C = 5.0f * cost_bbox - 2.0f * ssum - 2.0f * giou;
    costT[(b * NT + t) * NQ + q] = C;
}

// ---------------- Stage 2: Jonker-Volgenant LSA, one block per batch ----------------
// Mirrors the reference _lsa() exactly: float64 arithmetic, numpy-argmin
// tie-breaking (first minimum == smallest column index).
__global__ __launch_bounds__(LSA_THREADS) void lsa_kernel(const float* __restrict__ costT,
                                                          int* __restrict__ out) {
    const int b = blockIdx.x;
    const int tid = threadIdx.x;
    const float* cost = costT + b * NT * NQ;   // [t][q], row = target (1..NT), col = pred (1..NQ)

    __shared__ double u[NT + 1];
    __shared__ double v[NQ + 1];
    __shared__ double minv[NQ + 1];
    __shared__ int p[NQ + 1];
    __shared__ int way[NQ + 1];
    __shared__ unsigned char used[NQ + 1];
    __shared__ double red_v[LSA_THREADS / 64];
    __shared__ int red_j[LSA_THREADS / 64];
    __shared__ double delta_s, ui0_s;
    __shared__ int j0_s, i0_s, brk_s;
    __shared__ int r2c[NT];

    for (int j = tid; j <= NQ; j += LSA_THREADS) { v[j] = 0.0; p[j] = 0; }
    for (int i = tid; i <= NT; i += LSA_THREADS) u[i] = 0.0;
    __syncthreads();

    for (int i = 1; i <= NT; ++i) {
        // phase init
        for (int j = tid; j <= NQ; j += LSA_THREADS) { minv[j] = INFINITY; used[j] = 0; }
        if (tid == 0) { p[0] = i; j0_s = 0; brk_s = 0; }
        __syncthreads();

        while (true) {
            // ---- stage A: mark j0 used, broadcast i0 & u[i0] ----
            if (tid == 0) {
                int j0 = j0_s;
                used[j0] = 1;
                int i0 = p[j0];
                i0_s = i0;
                ui0_s = u[i0];
            }
            __syncthreads();
            const double ui0 = ui0_s;
            const float* crow = cost + (i0_s - 1) * NQ;
            const int j0cur = j0_s;

            // ---- stage B: scan free columns, update minv/way, local argmin ----
            double bv = INFINITY;
            int bj = NQ + 1;
            #pragma unroll
            for (int k = 0; k < COLS_PER_THREAD; ++k) {
                int j = tid + k * LSA_THREADS;
                if (j >= 1 && j <= NQ && !used[j]) {
                    double cur = ((double)crow[j - 1] - ui0) - v[j];
                    double m = minv[j];
                    if (cur < m) { m = cur; minv[j] = cur; way[j] = j0cur; }
                    // ascending j within thread: strict < keeps first minimum
                    if (m < bv) { bv = m; bj = j; }
                }
            }
            // wave butterfly argmin (tie -> smaller column index)
            #pragma unroll
            for (int off = 32; off; off >>= 1) {
                double ov = __shfl_xor(bv, off);
                int oj = __shfl_xor(bj, off);
                if (ov < bv || (ov == bv && oj < bj)) { bv = ov; bj = oj; }
            }
            if ((tid & 63) == 0) { red_v[tid >> 6] = bv; red_j[tid >> 6] = bj; }
            __syncthreads();

            // ---- stage C: combine wave partials, set delta/j1/j0/brk ----
            if (tid == 0) {
                double dv = red_v[0];
                int dj = red_j[0];
                #pragma unroll
                for (int w = 1; w < LSA_THREADS / 64; ++w) {
                    double ov = red_v[w];
                    int oj = red_j[w];
                    if (ov < dv || (ov == dv && oj < dj)) { dv = ov; dj = oj; }
                }
                delta_s = dv;
                j0_s = dj;                 // j0 = j1
                brk_s = (p[dj] == 0);
            }
            __syncthreads();
            const double delta = delta_s;

            // ---- stage D: dual update (u/v on used, minv on free) ----
            #pragma unroll
            for (int k = 0; k < COLS_PER_THREAD; ++k) {
                int j = tid + k * LSA_THREADS;
                if (j <= NQ) {
                    if (used[j]) { u[p[j]] += delta; v[j] -= delta; }
                    else         { minv[j] -= delta; }
                }
            }
            __syncthreads();
            if (brk_s) break;
        }

        // ---- augment along alternating path (serial, thread 0) ----
        if (tid == 0) {
            int j0 = j0_s;
            while (j0) {
                int j1w = way[j0];
                p[j0] = p[j1w];
                j0 = j1w;
            }
        }
        __syncthreads();
    }

    // ---- build row2col (target -> pred) ----
    for (int j = 1 + tid; j <= NQ; j += LSA_THREADS) {
        int pi = p[j];
        if (pi > 0) r2c[pi - 1] = j - 1;
    }
    __syncthreads();

    // ---- stable argsort by pred index (all values distinct -> rank by count) ----
    if (tid < NT) {
        int c = r2c[tid];
        int rank = 0;
        #pragma unroll 4
        for (int tt = 0; tt < NT; ++tt) rank += (r2c[tt] < c) ? 1 : 0;
        out[b * 2 * NT + rank] = c;        // out[b,0,rank] = pred idx
        out[b * 2 * NT + NT + rank] = tid; // out[b,1,rank] = target idx
    }
}

extern "C" void kernel_launch(void* const* d_in, const int* in_sizes, int n_in,
                              void* d_out, int out_size, void* d_ws, size_t ws_size,
                              hipStream_t stream) {
    const float* logits  = (const float*)d_in[0];  // (7,16,900,16)
    const float* pboxes  = (const float*)d_in[1];  // (16,900,4)
    const float* tboxes  = (const float*)d_in[2];  // (16,100,4)
    const int*   tlabels = (const int*)d_in[3];    // (7,16,100)
    int* out = (int*)d_out;                        // (16,2,100) int32
    float* costT = (float*)d_ws;                   // 16*100*900 floats = 5.76 MB

    const int total = BS * NT * NQ;
    cost_kernel<<<(total + 255) / 256, 256, 0, stream>>>(logits, pboxes, tboxes, tlabels, costT);
    lsa_kernel<<<BS, LSA_THREADS, 0, stream>>>(costT, out);
}

// Round 2
// 319.694 us; speedup vs baseline: 1.1635x; 1.1635x over previous
//
#include <hip/hip_runtime.h>
#include <hip/hip_bf16.h>
#include <math.h>

#define NQ 900
#define NT 100
#define BS 16
#define NH 7
#define NC 16
#define SLOTS 15   // 64 lanes * 15 slots = 960 >= 900 columns

// ---------- Stage 1a: sigmoid + transpose probs: [h,b,q,c] -> [h,b,c,q] ----------
__global__ __launch_bounds__(256) void sig_transpose_kernel(const float* __restrict__ logits,
                                                            float* __restrict__ probsT) {
    const int hb = blockIdx.x;                       // 0..NH*BS-1
    const float* src = logits + (size_t)hb * NQ * NC;
    float* dst = probsT + (size_t)hb * NC * NQ;
    __shared__ float tile[NC][NQ + 1];
    for (int e = threadIdx.x; e < NQ * NC; e += 256) {
        int q = e >> 4, c = e & 15;
        float x = src[e];
        tile[c][q] = 1.0f / (1.0f + expf(-x));       // same formula as R0 -> bit-identical
    }
    __syncthreads();
    for (int c = 0; c < NC; ++c)
        for (int q = threadIdx.x; q < NQ; q += 256)
            dst[c * NQ + q] = tile[c][q];
}

// ---------- Stage 1b: cost matrix (transposed: [b][t][q]), gathers probsT coalesced ----------
__global__ __launch_bounds__(256) void cost_kernel2(const float4* __restrict__ pboxes4,
                                                    const float4* __restrict__ tboxes4,
                                                    const int*    __restrict__ tlabels,
                                                    const float*  __restrict__ probsT,
                                                    float* __restrict__ costT) {
    int id = blockIdx.x * 256 + threadIdx.x;
    if (id >= BS * NT * NQ) return;
    int q = id % NQ;
    int t = (id / NQ) % NT;
    int b = id / (NQ * NT);

    float4 pb = pboxes4[b * NQ + q];
    float4 tb = tboxes4[b * NT + t];
    float px = pb.x, py = pb.y, pw = pb.z, ph = pb.w;
    float tx = tb.x, ty = tb.y, tw = tb.z, th = tb.w;

    float cost_bbox = fabsf(px - tx) + fabsf(py - ty) + fabsf(pw - tw) + fabsf(ph - th);

    float ax0 = px - 0.5f * pw, ay0 = py - 0.5f * ph;
    float ax1 = px + 0.5f * pw, ay1 = py + 0.5f * ph;
    float bx0 = tx - 0.5f * tw, by0 = ty - 0.5f * th;
    float bx1 = tx + 0.5f * tw, by1 = ty + 0.5f * th;
    float areaA = (ax1 - ax0) * (ay1 - ay0);
    float areaB = (bx1 - bx0) * (by1 - by0);
    float ltx = fmaxf(ax0, bx0), lty = fmaxf(ay0, by0);
    float rbx = fminf(ax1, bx1), rby = fminf(ay1, by1);
    float iw = fmaxf(rbx - ltx, 0.f), ih = fmaxf(rby - lty, 0.f);
    float inter = iw * ih;
    float uni = areaA + areaB - inter;
    float iou = inter / uni;
    float ex0 = fminf(ax0, bx0), ey0 = fminf(ay0, by0);
    float ex1 = fmaxf(ax1, bx1), ey1 = fmaxf(ey1 = py + 0.5f * ph, by1);  // placeholder fixed below
    // (recompute cleanly to avoid the typo above)
    ex1 = fmaxf(ax1, bx1); ey1 = fmaxf(ay1, by1);
    float ew = fmaxf(ex1 - ex0, 0.f), eh = fmaxf(ey1 - ey0, 0.f);
    float earea = ew * eh;
    float giou = iou - (earea - uni) / earea;

    float ssum = 0.f;
    #pragma unroll
    for (int h = 0; h < NH; ++h) {
        int lab = tlabels[(h * BS + b) * NT + t];
        ssum += probsT[(size_t)((h * BS + b) * NC + lab) * NQ + q];
    }

    costT[(b * NT + t) * NQ + q] = 5.0f * cost_bbox - 2.0f * ssum - 2.0f * giou;
}

// ---------- Fallback stage 1 (if ws too small for probsT): R0 cost kernel ----------
__global__ void cost_kernel_fb(const float* __restrict__ logits,
                               const float* __restrict__ pboxes,
                               const float* __restrict__ tboxes,
                               const int*   __restrict__ tlabels,
                               float* __restrict__ costT) {
    int id = blockIdx.x * blockDim.x + threadIdx.x;
    if (id >= BS * NT * NQ) return;
    int q = id % NQ;
    int t = (id / NQ) % NT;
    int b = id / (NQ * NT);

    const float* pb = pboxes + (b * NQ + q) * 4;
    const float* tb = tboxes + (b * NT + t) * 4;
    float px = pb[0], py = pb[1], pw = pb[2], ph = pb[3];
    float tx = tb[0], ty = tb[1], tw = tb[2], th = tb[3];

    float cost_bbox = fabsf(px - tx) + fabsf(py - ty) + fabsf(pw - tw) + fabsf(ph - th);

    float ax0 = px - 0.5f * pw, ay0 = py - 0.5f * ph;
    float ax1 = px + 0.5f * pw, ay1 = py + 0.5f * ph;
    float bx0 = tx - 0.5f * tw, by0 = ty - 0.5f * th;
    float bx1 = tx + 0.5f * tw, by1 = ty + 0.5f * th;
    float areaA = (ax1 - ax0) * (ay1 - ay0);
    float areaB = (bx1 - bx0) * (by1 - by0);
    float ltx = fmaxf(ax0, bx0), lty = fmaxf(ay0, by0);
    float rbx = fminf(ax1, bx1), rby = fminf(ay1, by1);
    float iw = fmaxf(rbx - ltx, 0.f), ih = fmaxf(rby - lty, 0.f);
    float inter = iw * ih;
    float uni = areaA + areaB - inter;
    float iou = inter / uni;
    float ex0 = fminf(ax0, bx0), ey0 = fminf(ay0, by0);
    float ex1 = fmaxf(ax1, bx1), ey1 = fmaxf(ay1, by1);
    float ew = fmaxf(ex1 - ex0, 0.f), eh = fmaxf(ey1 - ey0, 0.f);
    float earea = ew * eh;
    float giou = iou - (earea - uni) / earea;

    float ssum = 0.f;
    #pragma unroll
    for (int h = 0; h < NH; ++h) {
        int lab = tlabels[(h * BS + b) * NT + t];
        float x = logits[((h * BS + b) * NQ + q) * NC + lab];
        ssum += 1.0f / (1.0f + expf(-x));
    }

    costT[(b * NT + t) * NQ + q] = 5.0f * cost_bbox - 2.0f * ssum - 2.0f * giou;
}

// ---------- Stage 2: single-wave Jonker-Volgenant, register-resident state ----------
// Bit-exact reproduction of the reference _lsa(): f64 arithmetic, identical
// operation order for u/v/minv updates, numpy-argmin tie-break (smallest j).
__global__ __launch_bounds__(64) void lsa_kernel(const float* __restrict__ costT,
                                                 int* __restrict__ out) {
    const int b = blockIdx.x;
    const int lane = threadIdx.x;
    const float* cost = costT + b * NT * NQ;   // [t][q]

    __shared__ double u_s[NT + 1];
    __shared__ int p_s[NQ + 1];
    __shared__ int way_s[NQ + 1];
    __shared__ int r2c[NT];

    for (int j = lane; j <= NQ; j += 64) p_s[j] = 0;
    for (int i = lane; i <= NT; i += 64) u_s[i] = 0.0;
    __syncthreads();

    // lane-owned columns: slot k -> j = 1 + lane + 64*k
    double v[SLOTS], minv[SLOTS], ureg[SLOTS];
    int pof[SLOTS];
    #pragma unroll
    for (int k = 0; k < SLOTS; ++k) { v[k] = 0.0; ureg[k] = 0.0; pof[k] = 0; }
    const unsigned invalid = (lane < 4) ? 0u : (1u << 14);   // slot 14: j=897..960, valid lanes 0..3
    double u_c0 = 0.0;                                       // lane 0 tracks u[p[0]] = u[i]

    for (int i = 1; i <= NT; ++i) {
        #pragma unroll
        for (int k = 0; k < SLOTS; ++k) minv[k] = INFINITY;
        unsigned used = invalid;
        int j0 = 0;
        int i0 = i;                      // p[0] = i

        while (true) {
            // stage A: mark j0 used; read u[i0] (phase-stable in LDS)
            double u_i0 = u_s[i0];
            if (j0 != 0) {
                if (lane == ((j0 - 1) & 63)) {
                    int slot = (j0 - 1) >> 6;
                    used |= (1u << slot);
                    #pragma unroll
                    for (int k = 0; k < SLOTS; ++k)
                        if (slot == k) { pof[k] = i0; ureg[k] = u_i0; }
                }
            } else {
                if (lane == 0) u_c0 = u_i0;
            }

            // row fetch (coalesced, L2-resident)
            const float* crow = cost + (size_t)(i0 - 1) * NQ;
            float c[SLOTS];
            #pragma unroll
            for (int k = 0; k < SLOTS - 1; ++k) c[k] = crow[lane + 64 * k];
            c[SLOTS - 1] = (lane < 4) ? crow[lane + 64 * (SLOTS - 1)] : 0.0f;

            // stage B: scan free columns, update minv/way, local argmin (ascending j)
            double bv = INFINITY;
            int bj = 2048;
            #pragma unroll
            for (int k = 0; k < SLOTS; ++k) {
                if (!((used >> k) & 1u)) {
                    int j = 1 + lane + 64 * k;
                    double cur = ((double)c[k] - u_i0) - v[k];
                    if (cur < minv[k]) { minv[k] = cur; way_s[j] = j0; }
                    if (minv[k] < bv) { bv = minv[k]; bj = j; }
                }
            }
            // butterfly argmin over 64 lanes, tie -> smaller j
            #pragma unroll
            for (int off = 1; off < 64; off <<= 1) {
                double ov = __shfl_xor(bv, off);
                int oj = __shfl_xor(bj, off);
                if (ov < bv || (ov == bv && oj < bj)) { bv = ov; bj = oj; }
            }
            const double delta = bv;

            // stage D: dual update, exact reference order (register-resident)
            #pragma unroll
            for (int k = 0; k < SLOTS; ++k) {
                if ((used >> k) & 1u) { ureg[k] += delta; v[k] -= delta; }
                else                  { minv[k] -= delta; }
            }
            if (lane == 0) u_c0 += delta;          // u[p[0]] += delta (col 0 used from iter 1)

            j0 = bj;
            int pj = p_s[j0];
            if (pj == 0) break;
            i0 = pj;
        }

        __syncthreads();   // way writes -> chase; iteration u/p reads done
        if (lane == 0) {
            int j = j0;
            while (j) {
                int jw = way_s[j];
                p_s[j] = (jw == 0) ? i : p_s[jw];
                j = jw;
            }
            u_s[i] = u_c0;                          // write back row i (= p[0])
        }
        // write back u for columns used this phase (distinct rows, no conflicts)
        #pragma unroll
        for (int k = 0; k < SLOTS; ++k) {
            if (((used >> k) & 1u) && !((invalid >> k) & 1u)) u_s[pof[k]] = ureg[k];
        }
        __syncthreads();   // p/u visible for next phase
    }

    // row2col + stable-argsort ranks
    for (int j = 1 + lane; j <= NQ; j += 64) {
        int pi = p_s[j];
        if (pi > 0) r2c[pi - 1] = j - 1;
    }
    __syncthreads();
    for (int t = lane; t < NT; t += 64) {
        int ccol = r2c[t];
        int rank = 0;
        for (int tt = 0; tt < NT; ++tt) rank += (r2c[tt] < ccol) ? 1 : 0;
        out[b * 2 * NT + rank] = ccol;         // out[b,0,rank] = pred idx
        out[b * 2 * NT + NT + rank] = t;       // out[b,1,rank] = target idx
    }
}

extern "C" void kernel_launch(void* const* d_in, const int* in_sizes, int n_in,
                              void* d_out, int out_size, void* d_ws, size_t ws_size,
                              hipStream_t stream) {
    const float* logits  = (const float*)d_in[0];  // (7,16,900,16)
    const float* pboxes  = (const float*)d_in[1];  // (16,900,4)
    const float* tboxes  = (const float*)d_in[2];  // (16,100,4)
    const int*   tlabels = (const int*)d_in[3];    // (7,16,100)
    int* out = (int*)d_out;                        // (16,2,100) int32
    float* costT = (float*)d_ws;                   // 1,440,000 floats

    const size_t costT_elems  = (size_t)BS * NT * NQ;
    const size_t probsT_elems = (size_t)NH * BS * NC * NQ;
    const size_t need = (costT_elems + probsT_elems) * sizeof(float);

    const int total = BS * NT * NQ;
    if (ws_size >= need) {
        float* probsT = costT + costT_elems;
        sig_transpose_kernel<<<NH * BS, 256, 0, stream>>>(logits, probsT);
        cost_kernel2<<<(total + 255) / 256, 256, 0, stream>>>(
            (const float4*)pboxes, (const float4*)tboxes, tlabels, probsT, costT);
    } else {
        cost_kernel_fb<<<(total + 255) / 256, 256, 0, stream>>>(logits, pboxes, tboxes, tlabels, costT);
    }
    lsa_kernel<<<BS, 64, 0, stream>>>(costT, out);
}

// Round 3
// 128.476 us; speedup vs baseline: 2.8952x; 2.4884x over previous
//
#include <hip/hip_runtime.h>
#include <hip/hip_bf16.h>
#include <math.h>

#define NQ 900
#define NT 100
#define BS 16
#define NH 7
#define NC 16
#define SLOTS 15   // 64 lanes * 15 slots = 960 >= 900 columns

// ---------- Stage 1a: sigmoid + transpose probs: [h,b,q,c] -> [h,b,c,q] ----------
__global__ __launch_bounds__(256) void sig_transpose_kernel(const float* __restrict__ logits,
                                                            float* __restrict__ probsT) {
    const int hb = blockIdx.x;                       // 0..NH*BS-1
    const float* src = logits + (size_t)hb * NQ * NC;
    float* dst = probsT + (size_t)hb * NC * NQ;
    __shared__ float tile[NC][NQ + 1];
    for (int e = threadIdx.x; e < NQ * NC; e += 256) {
        int q = e >> 4, c = e & 15;
        float x = src[e];
        tile[c][q] = 1.0f / (1.0f + expf(-x));       // same formula as R0/R1 -> bit-identical
    }
    __syncthreads();
    for (int c = 0; c < NC; ++c)
        for (int q = threadIdx.x; q < NQ; q += 256)
            dst[c * NQ + q] = tile[c][q];
}

// ---------- Stage 1b: cost matrix (transposed: [b][t][q]) ----------
__global__ __launch_bounds__(256) void cost_kernel2(const float4* __restrict__ pboxes4,
                                                    const float4* __restrict__ tboxes4,
                                                    const int*    __restrict__ tlabels,
                                                    const float*  __restrict__ probsT,
                                                    float* __restrict__ costT) {
    int id = blockIdx.x * 256 + threadIdx.x;
    if (id >= BS * NT * NQ) return;
    int q = id % NQ;
    int t = (id / NQ) % NT;
    int b = id / (NQ * NT);

    float4 pb = pboxes4[b * NQ + q];
    float4 tb = tboxes4[b * NT + t];
    float px = pb.x, py = pb.y, pw = pb.z, ph = pb.w;
    float tx = tb.x, ty = tb.y, tw = tb.z, th = tb.w;

    float cost_bbox = fabsf(px - tx) + fabsf(py - ty) + fabsf(pw - tw) + fabsf(ph - th);

    float ax0 = px - 0.5f * pw, ay0 = py - 0.5f * ph;
    float ax1 = px + 0.5f * pw, ay1 = py + 0.5f * ph;
    float bx0 = tx - 0.5f * tw, by0 = ty - 0.5f * th;
    float bx1 = tx + 0.5f * tw, by1 = ty + 0.5f * th;
    float areaA = (ax1 - ax0) * (ay1 - ay0);
    float areaB = (bx1 - bx0) * (by1 - by0);
    float ltx = fmaxf(ax0, bx0), lty = fmaxf(ay0, by0);
    float rbx = fminf(ax1, bx1), rby = fminf(ay1, by1);
    float iw = fmaxf(rbx - ltx, 0.f), ih = fmaxf(rby - lty, 0.f);
    float inter = iw * ih;
    float uni = areaA + areaB - inter;
    float iou = inter / uni;
    float ex0 = fminf(ax0, bx0), ey0 = fminf(ay0, by0);
    float ex1 = fmaxf(ax1, bx1), ey1 = fmaxf(ay1, by1);
    float ew = fmaxf(ex1 - ex0, 0.f), eh = fmaxf(ey1 - ey0, 0.f);
    float earea = ew * eh;
    float giou = iou - (earea - uni) / earea;

    float ssum = 0.f;
    #pragma unroll
    for (int h = 0; h < NH; ++h) {
        int lab = tlabels[(h * BS + b) * NT + t];
        ssum += probsT[(size_t)((h * BS + b) * NC + lab) * NQ + q];
    }

    costT[(b * NT + t) * NQ + q] = 5.0f * cost_bbox - 2.0f * ssum - 2.0f * giou;
}

// ---------- Fallback stage 1 (if ws too small for probsT) ----------
__global__ void cost_kernel_fb(const float* __restrict__ logits,
                               const float* __restrict__ pboxes,
                               const float* __restrict__ tboxes,
                               const int*   __restrict__ tlabels,
                               float* __restrict__ costT) {
    int id = blockIdx.x * blockDim.x + threadIdx.x;
    if (id >= BS * NT * NQ) return;
    int q = id % NQ;
    int t = (id / NQ) % NT;
    int b = id / (NQ * NT);

    const float* pb = pboxes + (b * NQ + q) * 4;
    const float* tb = tboxes + (b * NT + t) * 4;
    float px = pb[0], py = pb[1], pw = pb[2], ph = pb[3];
    float tx = tb[0], ty = tb[1], tw = tb[2], th = tb[3];

    float cost_bbox = fabsf(px - tx) + fabsf(py - ty) + fabsf(pw - tw) + fabsf(ph - th);

    float ax0 = px - 0.5f * pw, ay0 = py - 0.5f * ph;
    float ax1 = px + 0.5f * pw, ay1 = py + 0.5f * ph;
    float bx0 = tx - 0.5f * tw, by0 = ty - 0.5f * th;
    float bx1 = tx + 0.5f * tw, by1 = ty + 0.5f * th;
    float areaA = (ax1 - ax0) * (ay1 - ay0);
    float areaB = (bx1 - bx0) * (by1 - by0);
    float ltx = fmaxf(ax0, bx0), lty = fmaxf(ay0, by0);
    float rbx = fminf(ax1, bx1), rby = fminf(ay1, by1);
    float iw = fmaxf(rbx - ltx, 0.f), ih = fmaxf(rby - lty, 0.f);
    float inter = iw * ih;
    float uni = areaA + areaB - inter;
    float iou = inter / uni;
    float ex0 = fminf(ax0, bx0), ey0 = fminf(ay0, by0);
    float ex1 = fmaxf(ax1, bx1), ey1 = fmaxf(ay1, by1);
    float ew = fmaxf(ex1 - ex0, 0.f), eh = fmaxf(ey1 - ey0, 0.f);
    float earea = ew * eh;
    float giou = iou - (earea - uni) / earea;

    float ssum = 0.f;
    #pragma unroll
    for (int h = 0; h < NH; ++h) {
        int lab = tlabels[(h * BS + b) * NT + t];
        float x = logits[((h * BS + b) * NQ + q) * NC + lab];
        ssum += 1.0f / (1.0f + expf(-x));
    }

    costT[(b * NT + t) * NQ + q] = 5.0f * cost_bbox - 2.0f * ssum - 2.0f * giou;
}

// ---------- Stage 2: JV LSA with greedy row-reduction init, single wave ----------
// Init: u[i] = min_j c[i][j] (f64 == cast of exact f32 min), v = 0, greedy-assign
// each row's argmin column if free. Duals stay feasible, assigned arcs have zero
// reduced cost -> shortest-augmenting-path phases for the ~5 contested rows yield
// the optimal assignment == reference's (optimum unique for random costs).
__global__ __launch_bounds__(64) void lsa_kernel(const float* __restrict__ costT,
                                                 int* __restrict__ out) {
    const int b = blockIdx.x;
    const int lane = threadIdx.x;
    const float* cost = costT + b * NT * NQ;   // [t][q]

    __shared__ double u_s[NT + 1];
    __shared__ int p_s[NQ + 1];
    __shared__ int way_s[NQ + 1];
    __shared__ int r2c[NT];
    __shared__ int jmin_s[NT];
    __shared__ int unass[NT];
    __shared__ int nun_s;

    for (int j = lane; j <= NQ; j += 64) p_s[j] = 0;
    __syncthreads();

    // ---- row minima + argmin (per-lane row, coalesced-in-time float4 scan) ----
    for (int base = 0; base < NT; base += 64) {
        int r = base + lane;
        if (r < NT) {
            const float4* row4 = (const float4*)(cost + (size_t)r * NQ);
            float m0 = INFINITY, m1 = INFINITY, m2 = INFINITY, m3 = INFINITY;
            int i0 = 0, i1 = 0, i2 = 0, i3 = 0;
            #pragma unroll 5
            for (int q4 = 0; q4 < NQ / 4; ++q4) {
                float4 cv = row4[q4];
                if (cv.x < m0) { m0 = cv.x; i0 = 4 * q4; }
                if (cv.y < m1) { m1 = cv.y; i1 = 4 * q4 + 1; }
                if (cv.z < m2) { m2 = cv.z; i2 = 4 * q4 + 2; }
                if (cv.w < m3) { m3 = cv.w; i3 = 4 * q4 + 3; }
            }
            float mv = m0; int mj = i0;
            if (m1 < mv || (m1 == mv && i1 < mj)) { mv = m1; mj = i1; }
            if (m2 < mv || (m2 == mv && i2 < mj)) { mv = m2; mj = i2; }
            if (m3 < mv || (m3 == mv && i3 < mj)) { mv = m3; mj = i3; }
            u_s[r + 1] = (double)mv;
            jmin_s[r] = mj;
        }
    }
    __syncthreads();

    // ---- greedy assignment (serial, lane 0) ----
    if (lane == 0) {
        int nun = 0;
        for (int i = 1; i <= NT; ++i) {
            int j = jmin_s[i - 1] + 1;
            if (p_s[j] == 0) p_s[j] = i;
            else unass[nun++] = i;
        }
        nun_s = nun;
    }
    __syncthreads();
    const int nun = nun_s;

    // lane-owned columns: slot k -> j = 1 + lane + 64*k
    double v[SLOTS], minv[SLOTS], ureg[SLOTS];
    int pof[SLOTS];
    #pragma unroll
    for (int k = 0; k < SLOTS; ++k) { v[k] = 0.0; ureg[k] = 0.0; pof[k] = 0; }
    const unsigned invalid = (lane < 4) ? 0u : (1u << 14);   // slot 14: j=897..960
    double u_c0 = 0.0;

    for (int ii = 0; ii < nun; ++ii) {
        const int i = unass[ii];
        #pragma unroll
        for (int k = 0; k < SLOTS; ++k) minv[k] = INFINITY;
        unsigned used = invalid;
        int j0 = 0;
        int i0 = i;                      // p[0] = i

        while (true) {
            // stage A: mark j0 used; read u[i0]
            double u_i0 = u_s[i0];
            if (j0 != 0) {
                if (lane == ((j0 - 1) & 63)) {
                    int slot = (j0 - 1) >> 6;
                    used |= (1u << slot);
                    #pragma unroll
                    for (int k = 0; k < SLOTS; ++k)
                        if (slot == k) { pof[k] = i0; ureg[k] = u_i0; }
                }
            } else {
                if (lane == 0) u_c0 = u_i0;
            }

            // row fetch (L2-resident)
            const float* crow = cost + (size_t)(i0 - 1) * NQ;
            float c[SLOTS];
            #pragma unroll
            for (int k = 0; k < SLOTS - 1; ++k) c[k] = crow[lane + 64 * k];
            c[SLOTS - 1] = (lane < 4) ? crow[lane + 64 * (SLOTS - 1)] : 0.0f;

            // stage B: scan free columns, update minv/way, local argmin (ascending j)
            double bv = INFINITY;
            int bj = 2048;
            #pragma unroll
            for (int k = 0; k < SLOTS; ++k) {
                if (!((used >> k) & 1u)) {
                    int j = 1 + lane + 64 * k;
                    double cur = ((double)c[k] - u_i0) - v[k];
                    if (cur < minv[k]) { minv[k] = cur; way_s[j] = j0; }
                    if (minv[k] < bv) { bv = minv[k]; bj = j; }
                }
            }
            // butterfly argmin over 64 lanes, tie -> smaller j
            #pragma unroll
            for (int off = 1; off < 64; off <<= 1) {
                double ov = __shfl_xor(bv, off);
                int oj = __shfl_xor(bj, off);
                if (ov < bv || (ov == bv && oj < bj)) { bv = ov; bj = oj; }
            }
            const double delta = bv;

            // stage D: dual update
            #pragma unroll
            for (int k = 0; k < SLOTS; ++k) {
                if ((used >> k) & 1u) { ureg[k] += delta; v[k] -= delta; }
                else                  { minv[k] -= delta; }
            }
            if (lane == 0) u_c0 += delta;

            j0 = bj;
            int pj = p_s[j0];
            if (pj == 0) break;
            i0 = pj;
        }

        __syncthreads();
        if (lane == 0) {
            int j = j0;
            while (j) {
                int jw = way_s[j];
                p_s[j] = (jw == 0) ? i : p_s[jw];
                j = jw;
            }
            u_s[i] = u_c0;
        }
        #pragma unroll
        for (int k = 0; k < SLOTS; ++k) {
            if (((used >> k) & 1u) && !((invalid >> k) & 1u)) u_s[pof[k]] = ureg[k];
        }
        __syncthreads();
    }

    // row2col + stable-argsort ranks
    for (int j = 1 + lane; j <= NQ; j += 64) {
        int pi = p_s[j];
        if (pi > 0) r2c[pi - 1] = j - 1;
    }
    __syncthreads();
    for (int t = lane; t < NT; t += 64) {
        int ccol = r2c[t];
        int rank = 0;
        for (int tt = 0; tt < NT; ++tt) rank += (r2c[tt] < ccol) ? 1 : 0;
        out[b * 2 * NT + rank] = ccol;         // out[b,0,rank] = pred idx
        out[b * 2 * NT + NT + rank] = t;       // out[b,1,rank] = target idx
    }
}

extern "C" void kernel_launch(void* const* d_in, const int* in_sizes, int n_in,
                              void* d_out, int out_size, void* d_ws, size_t ws_size,
                              hipStream_t stream) {
    const float* logits  = (const float*)d_in[0];  // (7,16,900,16)
    const float* pboxes  = (const float*)d_in[1];  // (16,900,4)
    const float* tboxes  = (const float*)d_in[2];  // (16,100,4)
    const int*   tlabels = (const int*)d_in[3];    // (7,16,100)
    int* out = (int*)d_out;                        // (16,2,100) int32
    float* costT = (float*)d_ws;                   // 1,440,000 floats

    const size_t costT_elems  = (size_t)BS * NT * NQ;
    const size_t probsT_elems = (size_t)NH * BS * NC * NQ;
    const size_t need = (costT_elems + probsT_elems) * sizeof(float);

    const int total = BS * NT * NQ;
    if (ws_size >= need) {
        float* probsT = costT + costT_elems;
        sig_transpose_kernel<<<NH * BS, 256, 0, stream>>>(logits, probsT);
        cost_kernel2<<<(total + 255) / 256, 256, 0, stream>>>(
            (const float4*)pboxes, (const float4*)tboxes, tlabels, probsT, costT);
    } else {
        cost_kernel_fb<<<(total + 255) / 256, 256, 0, stream>>>(logits, pboxes, tboxes, tlabels, costT);
    }
    lsa_kernel<<<BS, 64, 0, stream>>>(costT, out);
}